// Round 2
// baseline (1010.190 us; speedup 1.0000x reference)
//
#include <hip/hip_runtime.h>
#include <cstdint>

// ---------------------------------------------------------------------------
// TransformerLayer on MI355X (gfx950)
// Chunked pipeline (chunk C tokens, sized to ws_size; per-token ws = 9 KiB):
//   once: transpose-cast weights -> bf16 [N][K]
//   per chunk:
//     1. cast x -> bf16 (xb)
//     2. GEMM qkv = xb @ [Wq|Wk|Wv] + bias          (bf16 out, EPI=0)
//     3. attn (per-token 8x8) + residual + LN1 -> y (bf16)
//     4. GEMM h = relu(y @ W1 + b1)                 (bf16 out, EPI=1)
//     5. GEMM z = h @ W2 + b2 + y                   (fp32 out, EPI=2, z aliases qkv)
//     6. LN2(z) -> out (fp32)
// ---------------------------------------------------------------------------

typedef __attribute__((ext_vector_type(8))) short bf16x8;
typedef __attribute__((ext_vector_type(4))) float f32x4;
typedef __attribute__((ext_vector_type(8))) unsigned short u16x8;

__device__ __forceinline__ float bf2f(unsigned short u) {
  union { unsigned int i; float f; } v; v.i = ((unsigned int)u) << 16; return v.f;
}
__device__ __forceinline__ unsigned short f2bf(float f) {
  union { float f; unsigned int i; } v; v.f = f;
  unsigned int r = v.i + 0x7FFFu + ((v.i >> 16) & 1u);   // round-nearest-even
  return (unsigned short)(r >> 16);
}

#define GLD16(g, l)                                                         \
  __builtin_amdgcn_global_load_lds(                                         \
      (const __attribute__((address_space(1))) void*)(g),                   \
      (__attribute__((address_space(3))) void*)(l), 16, 0, 0)

// ---------------------------------------------------------------------------
// fp32 -> bf16 cast, 8 elements/thread, vectorized
// ---------------------------------------------------------------------------
__global__ __launch_bounds__(256) void cast_f32_bf16(
    const float* __restrict__ in, ushort* __restrict__ out) {
  const size_t i = (size_t)blockIdx.x * 256 + threadIdx.x;
  const float4* p = (const float4*)in + i * 2;
  float4 a = p[0], b = p[1];
  u16x8 r;
  r[0] = f2bf(a.x); r[1] = f2bf(a.y); r[2] = f2bf(a.z); r[3] = f2bf(a.w);
  r[4] = f2bf(b.x); r[5] = f2bf(b.y); r[6] = f2bf(b.z); r[7] = f2bf(b.w);
  ((u16x8*)out)[i] = r;
}

// ---------------------------------------------------------------------------
// Transpose-cast: W fp32 [K][Nn] row-major -> Wt bf16 [rowoff+Nn][ldt=K]
// ---------------------------------------------------------------------------
__global__ __launch_bounds__(256) void transpose_cast(
    const float* __restrict__ W, ushort* __restrict__ Wt,
    int K, int Nn, int rowoff, int ldt) {
  __shared__ float tile[32][33];
  const int tx = threadIdx.x & 31, ty = threadIdx.x >> 5;  // ty: 0..7
  const int nb = blockIdx.x * 32, kb = blockIdx.y * 32;
#pragma unroll
  for (int s = 0; s < 4; ++s)
    tile[ty + 8 * s][tx] = W[(size_t)(kb + ty + 8 * s) * Nn + nb + tx];
  __syncthreads();
#pragma unroll
  for (int s = 0; s < 4; ++s)
    Wt[(size_t)(rowoff + nb + ty + 8 * s) * ldt + kb + tx] =
        f2bf(tile[tx][ty + 8 * s]);
}

// ---------------------------------------------------------------------------
// bf16 GEMM, C = A[M,K] @ Bt[N,K]^T  (m97 structure: 128x128 tile, BK=64,
// 4 waves 2x2, each wave 64x64 = 4x4 frags of 16x16x32 MFMA,
// global_load_lds width-16 staging)
// EPI 0: +bias(select of 3 by n0/512), bf16 out   (QKV)
// EPI 1: relu(+bias), bf16 out                    (FFN1)
// EPI 2: +bias +resid(bf16), fp32 out             (FFN2)
// ---------------------------------------------------------------------------
template <int EPI>
__global__ __launch_bounds__(256) void gemm_bt(
    const ushort* __restrict__ A, const ushort* __restrict__ Bt,
    int N, int K, void* __restrict__ Cout,
    const float* __restrict__ bias0, const float* __restrict__ bias1,
    const float* __restrict__ bias2, const ushort* __restrict__ resid) {
  constexpr int BM = 128, BN = 128, BK = 64;
  __shared__ __align__(16) ushort As[BM * BK];
  __shared__ __align__(16) ushort Bs[BN * BK];
  const int tid = threadIdx.x;
  const int wid = tid >> 6, lane = tid & 63;
  const int wm = wid >> 1, wn = wid & 1;
  const size_t m0 = (size_t)blockIdx.y * BM;
  const size_t n0 = (size_t)blockIdx.x * BN;

  // staging: chunk c = i*256 + tid covers [128][64] row-major, 8 bf16/chunk.
  // LDS dest is wave-uniform base (+lane*16 in HW).
  const ushort* aG[4];
  const ushort* bG[4];
  ushort* aL[4];
  ushort* bL[4];
#pragma unroll
  for (int i = 0; i < 4; ++i) {
    int c = i * 256 + tid;
    int row = c >> 3, col = (c & 7) * 8;
    aG[i] = A + (m0 + row) * (size_t)K + col;
    bG[i] = Bt + (n0 + row) * (size_t)K + col;
    int base = (i * 256 + wid * 64) * 8;
    aL[i] = &As[base];
    bL[i] = &Bs[base];
  }

  f32x4 acc[4][4] = {};

  for (int k0 = 0; k0 < K; k0 += BK) {
#pragma unroll
    for (int i = 0; i < 4; ++i) GLD16(aG[i] + k0, aL[i]);
#pragma unroll
    for (int i = 0; i < 4; ++i) GLD16(bG[i] + k0, bL[i]);
    __syncthreads();
    const int kq = (lane >> 4) * 8;
    const int lm16 = lane & 15;
#pragma unroll
    for (int kk = 0; kk < BK; kk += 32) {
      bf16x8 af[4], bfr[4];
#pragma unroll
      for (int mi = 0; mi < 4; ++mi)
        af[mi] = *(const bf16x8*)&As[(wm * 64 + mi * 16 + lm16) * BK + kk + kq];
#pragma unroll
      for (int ni = 0; ni < 4; ++ni)
        bfr[ni] = *(const bf16x8*)&Bs[(wn * 64 + ni * 16 + lm16) * BK + kk + kq];
#pragma unroll
      for (int mi = 0; mi < 4; ++mi)
#pragma unroll
        for (int ni = 0; ni < 4; ++ni)
          acc[mi][ni] = __builtin_amdgcn_mfma_f32_16x16x32_bf16(
              af[mi], bfr[ni], acc[mi][ni], 0, 0, 0);
    }
    __syncthreads();
  }

  // epilogue: D col = lane&15, row = (lane>>4)*4 + j  (m89-verified)
  const int lm = lane & 15, lq = lane >> 4;
#pragma unroll
  for (int ni = 0; ni < 4; ++ni) {
    const size_t col = n0 + wn * 64 + ni * 16 + lm;
    float bv;
    if (EPI == 0) {
      const float* bp = (n0 < 512) ? bias0 : ((n0 < 1024) ? bias1 : bias2);
      bv = bp[col & 511];
    } else {
      bv = bias0[col];
    }
#pragma unroll
    for (int mi = 0; mi < 4; ++mi) {
#pragma unroll
      for (int j = 0; j < 4; ++j) {
        const size_t row = m0 + wm * 64 + mi * 16 + lq * 4 + j;
        float v = acc[mi][ni][j] + bv;
        if (EPI == 0) {
          ((ushort*)Cout)[row * N + col] = f2bf(v);
        } else if (EPI == 1) {
          ((ushort*)Cout)[row * N + col] = f2bf(fmaxf(v, 0.f));
        } else {
          v += bf2f(resid[row * N + col]);
          ((float*)Cout)[row * N + col] = v;
        }
      }
    }
  }
}

// ---------------------------------------------------------------------------
// Per-token attention (H=8, HD=64) + residual + LN1 -> y (bf16)
// One wave per token; lane = head-dim element d. All-register, shuffle-only.
// ---------------------------------------------------------------------------
__global__ __launch_bounds__(256) void attn_ln1(
    const ushort* __restrict__ qkv, const float* __restrict__ x,
    const float* __restrict__ g1, const float* __restrict__ b1,
    ushort* __restrict__ y) {
  const int lane = threadIdx.x & 63;
  const size_t t = (size_t)blockIdx.x * 4 + (threadIdx.x >> 6);
  const ushort* base = qkv + t * 1536;
  float qd[8], kd[8], vd[8];
#pragma unroll
  for (int h = 0; h < 8; ++h) {
    qd[h] = bf2f(base[h * 64 + lane]);
    kd[h] = bf2f(base[512 + h * 64 + lane]);
    vd[h] = bf2f(base[1024 + h * 64 + lane]);
  }
  // scores s[h][g] = (q_h . k_g) / 8 ; 64-lane butterfly reduce
  float s[8][8];
#pragma unroll
  for (int h = 0; h < 8; ++h) {
#pragma unroll
    for (int g = 0; g < 8; ++g) {
      float p = qd[h] * kd[g];
#pragma unroll
      for (int m = 1; m < 64; m <<= 1) p += __shfl_xor(p, m, 64);
      s[h][g] = p * 0.125f;
    }
  }
  // softmax over g (redundant per lane) + ctx + residual
  float r[8];
#pragma unroll
  for (int h = 0; h < 8; ++h) {
    float mx = s[h][0];
#pragma unroll
    for (int g = 1; g < 8; ++g) mx = fmaxf(mx, s[h][g]);
    float sum = 0.f;
#pragma unroll
    for (int g = 0; g < 8; ++g) { s[h][g] = __expf(s[h][g] - mx); sum += s[h][g]; }
    float c = 0.f;
#pragma unroll
    for (int g = 0; g < 8; ++g) c += s[h][g] * vd[g];
    r[h] = x[t * 512 + h * 64 + lane] + c / sum;
  }
  // LN1 over 512 = 8 regs x 64 lanes
  float sum = 0.f, sq = 0.f;
#pragma unroll
  for (int h = 0; h < 8; ++h) { sum += r[h]; sq += r[h] * r[h]; }
#pragma unroll
  for (int m = 1; m < 64; m <<= 1) {
    sum += __shfl_xor(sum, m, 64);
    sq += __shfl_xor(sq, m, 64);
  }
  const float mu = sum * (1.f / 512.f);
  const float var = sq * (1.f / 512.f) - mu * mu;
  const float rs = rsqrtf(var + 1e-5f);
#pragma unroll
  for (int h = 0; h < 8; ++h) {
    const int d = h * 64 + lane;
    y[t * 512 + d] = f2bf((r[h] - mu) * rs * g1[d] + b1[d]);
  }
}

// ---------------------------------------------------------------------------
// LN2(z) -> out fp32. One wave per token.
// ---------------------------------------------------------------------------
__global__ __launch_bounds__(256) void ln_out(
    const float* __restrict__ z, const float* __restrict__ g2,
    const float* __restrict__ b2, float* __restrict__ out) {
  const int lane = threadIdx.x & 63;
  const size_t t = (size_t)blockIdx.x * 4 + (threadIdx.x >> 6);
  float r[8];
  float sum = 0.f, sq = 0.f;
#pragma unroll
  for (int h = 0; h < 8; ++h) {
    r[h] = z[t * 512 + h * 64 + lane];
    sum += r[h];
    sq += r[h] * r[h];
  }
#pragma unroll
  for (int m = 1; m < 64; m <<= 1) {
    sum += __shfl_xor(sum, m, 64);
    sq += __shfl_xor(sq, m, 64);
  }
  const float mu = sum * (1.f / 512.f);
  const float rs = rsqrtf(sq * (1.f / 512.f) - mu * mu + 1e-5f);
#pragma unroll
  for (int h = 0; h < 8; ++h) {
    const int d = h * 64 + lane;
    out[t * 512 + d] = (r[h] - mu) * rs * g2[d] + b2[d];
  }
}

// ---------------------------------------------------------------------------
extern "C" void kernel_launch(void* const* d_in, const int* in_sizes, int n_in,
                              void* d_out, int out_size, void* d_ws,
                              size_t ws_size, hipStream_t stream) {
  const float* x    = (const float*)d_in[0];
  const float* Wq   = (const float*)d_in[1];
  const float* bq   = (const float*)d_in[2];
  const float* Wk   = (const float*)d_in[3];
  const float* bk   = (const float*)d_in[4];
  const float* Wv   = (const float*)d_in[5];
  const float* bv   = (const float*)d_in[6];
  const float* ln1g = (const float*)d_in[7];
  const float* ln1b = (const float*)d_in[8];
  const float* W1   = (const float*)d_in[9];
  const float* b1   = (const float*)d_in[10];
  const float* W2   = (const float*)d_in[11];
  const float* b2   = (const float*)d_in[12];
  const float* ln2g = (const float*)d_in[13];
  const float* ln2b = (const float*)d_in[14];
  float* out = (float*)d_out;

  const int Ntok = in_sizes[0] / 512;  // 65536

  // ---- workspace layout: weights once, then chunk buffers (9 KiB/token)
  char* ws = (char*)d_ws;
  ushort* Wqkvt = (ushort*)ws;                       // [1536][512]
  ushort* W1t   = Wqkvt + (size_t)1536 * 512;        // [2048][512]
  ushort* W2t   = W1t + (size_t)2048 * 512;          // [512][2048]
  const size_t woff = ((size_t)1536 * 512 + (size_t)2048 * 512 +
                       (size_t)512 * 2048) * 2;      // 5.5 MiB

  size_t avail = (ws_size > woff) ? (ws_size - woff) : 0;
  long long Cll = (long long)(avail / 9216);         // bytes/token in chunk bufs
  Cll = (Cll / 128) * 128;
  if (Cll > 16384) Cll = 16384;
  if (Cll > Ntok) Cll = Ntok;
  if (Cll < 128) Cll = 128;                           // last resort
  const int C = (int)Cll;

  char* cb = ws + woff;
  ushort* xb  = (ushort*)cb;                          // [C][512] bf16
  ushort* y   = xb + (size_t)C * 512;                 // [C][512] bf16
  ushort* qkv = y + (size_t)C * 512;                  // [C][1536] bf16
  ushort* hb  = qkv + (size_t)C * 1536;               // [C][2048] bf16
  float*  z   = (float*)qkv;                          // [C][512] f32 (aliases qkv)

  // ---- weight transposes (once)
  transpose_cast<<<dim3(16, 16), dim3(256), 0, stream>>>(Wq, Wqkvt, 512, 512, 0, 512);
  transpose_cast<<<dim3(16, 16), dim3(256), 0, stream>>>(Wk, Wqkvt, 512, 512, 512, 512);
  transpose_cast<<<dim3(16, 16), dim3(256), 0, stream>>>(Wv, Wqkvt, 512, 512, 1024, 512);
  transpose_cast<<<dim3(64, 16), dim3(256), 0, stream>>>(W1, W1t, 512, 2048, 0, 512);
  transpose_cast<<<dim3(16, 64), dim3(256), 0, stream>>>(W2, W2t, 2048, 512, 0, 2048);

  // ---- chunked pipeline
  for (int t0 = 0; t0 < Ntok; t0 += C) {
    const int Cc = (Ntok - t0 < C) ? (Ntok - t0) : C;   // multiple of 128
    const float* xc = x + (size_t)t0 * 512;

    cast_f32_bf16<<<dim3((Cc * 512) / 2048), dim3(256), 0, stream>>>(xc, xb);

    gemm_bt<0><<<dim3(1536 / 128, Cc / 128), dim3(256), 0, stream>>>(
        xb, Wqkvt, 1536, 512, qkv, bq, bk, bv, nullptr);

    attn_ln1<<<dim3(Cc / 4), dim3(256), 0, stream>>>(qkv, xc, ln1g, ln1b, y);

    gemm_bt<1><<<dim3(2048 / 128, Cc / 128), dim3(256), 0, stream>>>(
        y, W1t, 2048, 512, hb, b1, nullptr, nullptr, nullptr);

    gemm_bt<2><<<dim3(512 / 128, Cc / 128), dim3(256), 0, stream>>>(
        hb, W2t, 512, 2048, z, b2, nullptr, nullptr, y);

    ln_out<<<dim3(Cc / 4), dim3(256), 0, stream>>>(
        z, ln2g, ln2b, out + (size_t)t0 * 512);
  }
}

// Round 3
// 820.595 us; speedup vs baseline: 1.2310x; 1.2310x over previous
//
#include <hip/hip_runtime.h>
#include <cstdint>

// ---------------------------------------------------------------------------
// TransformerLayer on MI355X (gfx950)
// Chunked pipeline (chunk C tokens, sized to ws_size; per-token ws = 9 KiB):
//   once: transpose-cast weights -> bf16 [N][K]
//   per chunk:
//     1. cast x -> bf16 (xb)
//     2. GEMM qkv = xb @ [Wq|Wk|Wv] + bias          (bf16 out, EPI=0)
//     3. attn (per-token 8x8) + residual + LN1 -> y (bf16)
//     4. GEMM h = relu(y @ W1 + b1)                 (bf16 out, EPI=1)
//     5. GEMM z = h @ W2 + b2 + y                   (fp32 out, EPI=2, z aliases qkv)
//     6. LN2(z) -> out (fp32)
// ---------------------------------------------------------------------------

typedef __attribute__((ext_vector_type(8))) short bf16x8;
typedef __attribute__((ext_vector_type(4))) float f32x4;
typedef __attribute__((ext_vector_type(8))) unsigned short u16x8;

__device__ __forceinline__ float bf2f(unsigned short u) {
  union { unsigned int i; float f; } v; v.i = ((unsigned int)u) << 16; return v.f;
}
__device__ __forceinline__ unsigned short f2bf(float f) {
  union { float f; unsigned int i; } v; v.f = f;
  unsigned int r = v.i + 0x7FFFu + ((v.i >> 16) & 1u);   // round-nearest-even
  return (unsigned short)(r >> 16);
}

#define GLD16(g, l)                                                         \
  __builtin_amdgcn_global_load_lds(                                         \
      (const __attribute__((address_space(1))) void*)(g),                   \
      (__attribute__((address_space(3))) void*)(l), 16, 0, 0)

// ---------------------------------------------------------------------------
// fp32 -> bf16 cast, 8 elements/thread, vectorized
// ---------------------------------------------------------------------------
__global__ __launch_bounds__(256) void cast_f32_bf16(
    const float* __restrict__ in, ushort* __restrict__ out) {
  const size_t i = (size_t)blockIdx.x * 256 + threadIdx.x;
  const float4* p = (const float4*)in + i * 2;
  float4 a = p[0], b = p[1];
  u16x8 r;
  r[0] = f2bf(a.x); r[1] = f2bf(a.y); r[2] = f2bf(a.z); r[3] = f2bf(a.w);
  r[4] = f2bf(b.x); r[5] = f2bf(b.y); r[6] = f2bf(b.z); r[7] = f2bf(b.w);
  ((u16x8*)out)[i] = r;
}

// ---------------------------------------------------------------------------
// Transpose-cast: W fp32 [K][Nn] row-major -> Wt bf16 [rowoff+Nn][ldt=K]
// ---------------------------------------------------------------------------
__global__ __launch_bounds__(256) void transpose_cast(
    const float* __restrict__ W, ushort* __restrict__ Wt,
    int K, int Nn, int rowoff, int ldt) {
  __shared__ float tile[32][33];
  const int tx = threadIdx.x & 31, ty = threadIdx.x >> 5;  // ty: 0..7
  const int nb = blockIdx.x * 32, kb = blockIdx.y * 32;
#pragma unroll
  for (int s = 0; s < 4; ++s)
    tile[ty + 8 * s][tx] = W[(size_t)(kb + ty + 8 * s) * Nn + nb + tx];
  __syncthreads();
#pragma unroll
  for (int s = 0; s < 4; ++s)
    Wt[(size_t)(rowoff + nb + ty + 8 * s) * ldt + kb + tx] =
        f2bf(tile[tx][ty + 8 * s]);
}

// ---------------------------------------------------------------------------
// bf16 GEMM, C = A[M,K] @ Bt[N,K]^T  (m97 structure: 128x128 tile, BK=64,
// 4 waves 2x2, each wave 64x64 = 4x4 frags of 16x16x32 MFMA,
// global_load_lds width-16 staging)
// ---------------------------------------------------------------------------
template <int EPI>
__global__ __launch_bounds__(256) void gemm_bt(
    const ushort* __restrict__ A, const ushort* __restrict__ Bt,
    int N, int K, void* __restrict__ Cout,
    const float* __restrict__ bias0, const float* __restrict__ bias1,
    const float* __restrict__ bias2, const ushort* __restrict__ resid) {
  constexpr int BM = 128, BN = 128, BK = 64;
  __shared__ __align__(16) ushort As[BM * BK];
  __shared__ __align__(16) ushort Bs[BN * BK];
  const int tid = threadIdx.x;
  const int wid = tid >> 6, lane = tid & 63;
  const int wm = wid >> 1, wn = wid & 1;
  const size_t m0 = (size_t)blockIdx.y * BM;
  const size_t n0 = (size_t)blockIdx.x * BN;

  const ushort* aG[4];
  const ushort* bG[4];
  ushort* aL[4];
  ushort* bL[4];
#pragma unroll
  for (int i = 0; i < 4; ++i) {
    int c = i * 256 + tid;
    int row = c >> 3, col = (c & 7) * 8;
    aG[i] = A + (m0 + row) * (size_t)K + col;
    bG[i] = Bt + (n0 + row) * (size_t)K + col;
    int base = (i * 256 + wid * 64) * 8;
    aL[i] = &As[base];
    bL[i] = &Bs[base];
  }

  f32x4 acc[4][4] = {};

  for (int k0 = 0; k0 < K; k0 += BK) {
#pragma unroll
    for (int i = 0; i < 4; ++i) GLD16(aG[i] + k0, aL[i]);
#pragma unroll
    for (int i = 0; i < 4; ++i) GLD16(bG[i] + k0, bL[i]);
    __syncthreads();
    const int kq = (lane >> 4) * 8;
    const int lm16 = lane & 15;
#pragma unroll
    for (int kk = 0; kk < BK; kk += 32) {
      bf16x8 af[4], bfr[4];
#pragma unroll
      for (int mi = 0; mi < 4; ++mi)
        af[mi] = *(const bf16x8*)&As[(wm * 64 + mi * 16 + lm16) * BK + kk + kq];
#pragma unroll
      for (int ni = 0; ni < 4; ++ni)
        bfr[ni] = *(const bf16x8*)&Bs[(wn * 64 + ni * 16 + lm16) * BK + kk + kq];
#pragma unroll
      for (int mi = 0; mi < 4; ++mi)
#pragma unroll
        for (int ni = 0; ni < 4; ++ni)
          acc[mi][ni] = __builtin_amdgcn_mfma_f32_16x16x32_bf16(
              af[mi], bfr[ni], acc[mi][ni], 0, 0, 0);
    }
    __syncthreads();
  }

  const int lm = lane & 15, lq = lane >> 4;
#pragma unroll
  for (int ni = 0; ni < 4; ++ni) {
    const size_t col = n0 + wn * 64 + ni * 16 + lm;
    float bv;
    if (EPI == 0) {
      const float* bp = (n0 < 512) ? bias0 : ((n0 < 1024) ? bias1 : bias2);
      bv = bp[col & 511];
    } else {
      bv = bias0[col];
    }
#pragma unroll
    for (int mi = 0; mi < 4; ++mi) {
#pragma unroll
      for (int j = 0; j < 4; ++j) {
        const size_t row = m0 + wm * 64 + mi * 16 + lq * 4 + j;
        float v = acc[mi][ni][j] + bv;
        if (EPI == 0) {
          ((ushort*)Cout)[row * N + col] = f2bf(v);
        } else if (EPI == 1) {
          ((ushort*)Cout)[row * N + col] = f2bf(fmaxf(v, 0.f));
        } else {
          v += bf2f(resid[row * N + col]);
          ((float*)Cout)[row * N + col] = v;
        }
      }
    }
  }
}

// ---------------------------------------------------------------------------
// Per-token attention (H=8, HD=64) + residual + LN1 -> y (bf16)
// One wave per token; lane = head-dim element d.
// Scores via 6-step transpose-reduce (63 shuffles total instead of 384):
// after step k, value f in a lane corresponds to score index
// i = (f<<(k+1)) | (lane & ((2<<k)-1)); final: lane l holds score i=l=h*8+g.
// Softmax in 8-lane groups (masks 1/2/4). Context via v_readlane broadcast.
// ---------------------------------------------------------------------------
__global__ __launch_bounds__(256) void attn_ln1(
    const ushort* __restrict__ qkv, const float* __restrict__ x,
    const float* __restrict__ g1, const float* __restrict__ b1,
    ushort* __restrict__ y) {
  const int lane = threadIdx.x & 63;
  const size_t t = (size_t)blockIdx.x * 4 + (threadIdx.x >> 6);
  const ushort* base = qkv + t * 1536;
  float qd[8], kd[8], vd[8];
#pragma unroll
  for (int h = 0; h < 8; ++h) {
    qd[h] = bf2f(base[h * 64 + lane]);
    kd[h] = bf2f(base[512 + h * 64 + lane]);
    vd[h] = bf2f(base[1024 + h * 64 + lane]);
  }

  const bool lb0 = lane & 1, lb1 = lane & 2, lb2 = lane & 4;
  const bool lb3 = lane & 8, lb4 = lane & 16, lb5 = lane & 32;

  // step 0 fused with product generation: i = h*8+g
  float c1[32];
#pragma unroll
  for (int f = 0; f < 32; ++f) {
    const int i0 = 2 * f, i1 = 2 * f + 1;
    const float a0 = qd[i0 >> 3] * kd[i0 & 7];
    const float a1 = qd[i1 >> 3] * kd[i1 & 7];
    const float keep = lb0 ? a1 : a0;
    const float send = lb0 ? a0 : a1;
    c1[f] = keep + __shfl_xor(send, 1, 64);
  }
  float c2[16];
#pragma unroll
  for (int f = 0; f < 16; ++f) {
    const float keep = lb1 ? c1[2 * f + 1] : c1[2 * f];
    const float send = lb1 ? c1[2 * f] : c1[2 * f + 1];
    c2[f] = keep + __shfl_xor(send, 2, 64);
  }
  float c3[8];
#pragma unroll
  for (int f = 0; f < 8; ++f) {
    const float keep = lb2 ? c2[2 * f + 1] : c2[2 * f];
    const float send = lb2 ? c2[2 * f] : c2[2 * f + 1];
    c3[f] = keep + __shfl_xor(send, 4, 64);
  }
  float c4[4];
#pragma unroll
  for (int f = 0; f < 4; ++f) {
    const float keep = lb3 ? c3[2 * f + 1] : c3[2 * f];
    const float send = lb3 ? c3[2 * f] : c3[2 * f + 1];
    c4[f] = keep + __shfl_xor(send, 8, 64);
  }
  float c5[2];
#pragma unroll
  for (int f = 0; f < 2; ++f) {
    const float keep = lb4 ? c4[2 * f + 1] : c4[2 * f];
    const float send = lb4 ? c4[2 * f] : c4[2 * f + 1];
    c5[f] = keep + __shfl_xor(send, 16, 64);
  }
  const float keep = lb5 ? c5[1] : c5[0];
  const float send = lb5 ? c5[0] : c5[1];
  const float s = keep + __shfl_xor(send, 32, 64);  // raw score, i = lane

  // softmax over g (lanes within 8-lane group), scale 1/sqrt(64)=0.125
  float mx = s;
  mx = fmaxf(mx, __shfl_xor(mx, 1, 64));
  mx = fmaxf(mx, __shfl_xor(mx, 2, 64));
  mx = fmaxf(mx, __shfl_xor(mx, 4, 64));
  const float e = __expf((s - mx) * 0.125f);
  float sum = e;
  sum += __shfl_xor(sum, 1, 64);
  sum += __shfl_xor(sum, 2, 64);
  sum += __shfl_xor(sum, 4, 64);
  const float a = e * __builtin_amdgcn_rcpf(sum);  // attn weight for (h,g)=lane

  // context: every lane (as d) needs all 64 weights -> readlane broadcast
  const int ai = __float_as_int(a);
  float r[8];
#pragma unroll
  for (int h = 0; h < 8; ++h) {
    float c = 0.f;
#pragma unroll
    for (int g = 0; g < 8; ++g) {
      const float w = __int_as_float(__builtin_amdgcn_readlane(ai, h * 8 + g));
      c = fmaf(w, vd[g], c);
    }
    r[h] = x[t * 512 + h * 64 + lane] + c;
  }

  // LN1 over 512 = 8 regs x 64 lanes
  float sm = 0.f, sq = 0.f;
#pragma unroll
  for (int h = 0; h < 8; ++h) { sm += r[h]; sq += r[h] * r[h]; }
#pragma unroll
  for (int m = 1; m < 64; m <<= 1) {
    sm += __shfl_xor(sm, m, 64);
    sq += __shfl_xor(sq, m, 64);
  }
  const float mu = sm * (1.f / 512.f);
  const float var = sq * (1.f / 512.f) - mu * mu;
  const float rs = rsqrtf(var + 1e-5f);
#pragma unroll
  for (int h = 0; h < 8; ++h) {
    const int d = h * 64 + lane;
    y[t * 512 + d] = f2bf((r[h] - mu) * rs * g1[d] + b1[d]);
  }
}

// ---------------------------------------------------------------------------
// LN2(z) -> out fp32. One wave per token, float4-vectorized.
// ---------------------------------------------------------------------------
__global__ __launch_bounds__(256) void ln_out(
    const float* __restrict__ z, const float* __restrict__ g2,
    const float* __restrict__ b2, float* __restrict__ out) {
  const int lane = threadIdx.x & 63;
  const size_t t = (size_t)blockIdx.x * 4 + (threadIdx.x >> 6);
  const float4* zp = (const float4*)(z + t * 512);
  const float4 r0 = zp[lane], r1 = zp[lane + 64];
  float sm = r0.x + r0.y + r0.z + r0.w + r1.x + r1.y + r1.z + r1.w;
  float sq = r0.x * r0.x + r0.y * r0.y + r0.z * r0.z + r0.w * r0.w +
             r1.x * r1.x + r1.y * r1.y + r1.z * r1.z + r1.w * r1.w;
#pragma unroll
  for (int m = 1; m < 64; m <<= 1) {
    sm += __shfl_xor(sm, m, 64);
    sq += __shfl_xor(sq, m, 64);
  }
  const float mu = sm * (1.f / 512.f);
  const float rs = rsqrtf(sq * (1.f / 512.f) - mu * mu + 1e-5f);
  const float4* g4 = (const float4*)g2;
  const float4* b4 = (const float4*)b2;
  float4* o4 = (float4*)(out + t * 512);
  const float4 ga = g4[lane], gb = g4[lane + 64];
  const float4 ba = b4[lane], bb = b4[lane + 64];
  float4 oa, ob;
  oa.x = (r0.x - mu) * rs * ga.x + ba.x;
  oa.y = (r0.y - mu) * rs * ga.y + ba.y;
  oa.z = (r0.z - mu) * rs * ga.z + ba.z;
  oa.w = (r0.w - mu) * rs * ga.w + ba.w;
  ob.x = (r1.x - mu) * rs * gb.x + bb.x;
  ob.y = (r1.y - mu) * rs * gb.y + bb.y;
  ob.z = (r1.z - mu) * rs * gb.z + bb.z;
  ob.w = (r1.w - mu) * rs * gb.w + bb.w;
  o4[lane] = oa;
  o4[lane + 64] = ob;
}

// ---------------------------------------------------------------------------
extern "C" void kernel_launch(void* const* d_in, const int* in_sizes, int n_in,
                              void* d_out, int out_size, void* d_ws,
                              size_t ws_size, hipStream_t stream) {
  const float* x    = (const float*)d_in[0];
  const float* Wq   = (const float*)d_in[1];
  const float* bq   = (const float*)d_in[2];
  const float* Wk   = (const float*)d_in[3];
  const float* bk   = (const float*)d_in[4];
  const float* Wv   = (const float*)d_in[5];
  const float* bv   = (const float*)d_in[6];
  const float* ln1g = (const float*)d_in[7];
  const float* ln1b = (const float*)d_in[8];
  const float* W1   = (const float*)d_in[9];
  const float* b1   = (const float*)d_in[10];
  const float* W2   = (const float*)d_in[11];
  const float* b2   = (const float*)d_in[12];
  const float* ln2g = (const float*)d_in[13];
  const float* ln2b = (const float*)d_in[14];
  float* out = (float*)d_out;

  const int Ntok = in_sizes[0] / 512;  // 65536

  // ---- workspace layout: weights once, then chunk buffers (9 KiB/token)
  char* ws = (char*)d_ws;
  ushort* Wqkvt = (ushort*)ws;                       // [1536][512]
  ushort* W1t   = Wqkvt + (size_t)1536 * 512;        // [2048][512]
  ushort* W2t   = W1t + (size_t)2048 * 512;          // [512][2048]
  const size_t woff = ((size_t)1536 * 512 + (size_t)2048 * 512 +
                       (size_t)512 * 2048) * 2;      // 5.5 MiB

  size_t avail = (ws_size > woff) ? (ws_size - woff) : 0;
  long long Cll = (long long)(avail / 9216);
  Cll = (Cll / 128) * 128;
  if (Cll > 16384) Cll = 16384;
  if (Cll > Ntok) Cll = Ntok;
  if (Cll < 128) Cll = 128;
  const int C = (int)Cll;

  char* cb = ws + woff;
  ushort* xb  = (ushort*)cb;                          // [C][512] bf16
  ushort* y   = xb + (size_t)C * 512;                 // [C][512] bf16
  ushort* qkv = y + (size_t)C * 512;                  // [C][1536] bf16
  ushort* hb  = qkv + (size_t)C * 1536;               // [C][2048] bf16
  float*  z   = (float*)qkv;                          // [C][512] f32 (aliases qkv)

  // ---- weight transposes (once)
  transpose_cast<<<dim3(16, 16), dim3(256), 0, stream>>>(Wq, Wqkvt, 512, 512, 0, 512);
  transpose_cast<<<dim3(16, 16), dim3(256), 0, stream>>>(Wk, Wqkvt, 512, 512, 512, 512);
  transpose_cast<<<dim3(16, 16), dim3(256), 0, stream>>>(Wv, Wqkvt, 512, 512, 1024, 512);
  transpose_cast<<<dim3(64, 16), dim3(256), 0, stream>>>(W1, W1t, 512, 2048, 0, 512);
  transpose_cast<<<dim3(16, 64), dim3(256), 0, stream>>>(W2, W2t, 2048, 512, 0, 2048);

  // ---- chunked pipeline
  for (int t0 = 0; t0 < Ntok; t0 += C) {
    const int Cc = (Ntok - t0 < C) ? (Ntok - t0) : C;   // multiple of 128
    const float* xc = x + (size_t)t0 * 512;

    cast_f32_bf16<<<dim3((Cc * 512) / 2048), dim3(256), 0, stream>>>(xc, xb);

    gemm_bt<0><<<dim3(1536 / 128, Cc / 128), dim3(256), 0, stream>>>(
        xb, Wqkvt, 1536, 512, qkv, bq, bk, bv, nullptr);

    attn_ln1<<<dim3(Cc / 4), dim3(256), 0, stream>>>(qkv, xc, ln1g, ln1b, y);

    gemm_bt<1><<<dim3(2048 / 128, Cc / 128), dim3(256), 0, stream>>>(
        y, W1t, 2048, 512, hb, b1, nullptr, nullptr, nullptr);

    gemm_bt<2><<<dim3(512 / 128, Cc / 128), dim3(256), 0, stream>>>(
        hb, W2t, 512, 2048, z, b2, nullptr, nullptr, y);

    ln_out<<<dim3(Cc / 4), dim3(256), 0, stream>>>(
        z, ln2g, ln2b, out + (size_t)t0 * 512);
  }
}

// Round 4
// 780.913 us; speedup vs baseline: 1.2936x; 1.0508x over previous
//
#include <hip/hip_runtime.h>
#include <cstdint>

// ---------------------------------------------------------------------------
// TransformerLayer on MI355X (gfx950)
// Chunked pipeline (chunk C tokens, per-token ws = 9 KiB):
//   once: transpose-cast weights -> bf16 [N][K]
//   per chunk:
//     1. cast x -> bf16 (xb)
//     2. GEMM qkv = xb @ [Wq|Wk|Wv] + bias          (bf16 out, EPI=0)
//     3. attn (per-token 8x8) + residual + LN1 -> y (bf16)
//     4. GEMM h = relu(y @ W1 + b1)                 (bf16 out, EPI=1)
//     5. GEMM z = h @ W2 + b2 + y                   (fp32 out, EPI=2, z aliases qkv)
//     6. LN2(z) -> out (fp32)
// GEMM: 256x256 tile, BK=32, quad-buffered LDS (128 KiB), counted vmcnt(8)
// pipeline (T3+T4), granule-swizzled LDS (T2), setprio around MFMA (T5).
// ---------------------------------------------------------------------------

typedef __attribute__((ext_vector_type(8))) short bf16x8;
typedef __attribute__((ext_vector_type(4))) float f32x4;
typedef __attribute__((ext_vector_type(8))) unsigned short u16x8;

__device__ __forceinline__ float bf2f(unsigned short u) {
  union { unsigned int i; float f; } v; v.i = ((unsigned int)u) << 16; return v.f;
}
__device__ __forceinline__ unsigned short f2bf(float f) {
  union { float f; unsigned int i; } v; v.f = f;
  unsigned int r = v.i + 0x7FFFu + ((v.i >> 16) & 1u);   // round-nearest-even
  return (unsigned short)(r >> 16);
}

#define GLD16(g, l)                                                         \
  __builtin_amdgcn_global_load_lds(                                         \
      (const __attribute__((address_space(1))) void*)(g),                   \
      (__attribute__((address_space(3))) void*)(l), 16, 0, 0)

// ---------------------------------------------------------------------------
// fp32 -> bf16 cast, 8 elements/thread, vectorized
// ---------------------------------------------------------------------------
__global__ __launch_bounds__(256) void cast_f32_bf16(
    const float* __restrict__ in, ushort* __restrict__ out) {
  const size_t i = (size_t)blockIdx.x * 256 + threadIdx.x;
  const float4* p = (const float4*)in + i * 2;
  float4 a = p[0], b = p[1];
  u16x8 r;
  r[0] = f2bf(a.x); r[1] = f2bf(a.y); r[2] = f2bf(a.z); r[3] = f2bf(a.w);
  r[4] = f2bf(b.x); r[5] = f2bf(b.y); r[6] = f2bf(b.z); r[7] = f2bf(b.w);
  ((u16x8*)out)[i] = r;
}

// ---------------------------------------------------------------------------
// Transpose-cast: W fp32 [K][Nn] row-major -> Wt bf16 [rowoff+Nn][ldt=K]
// ---------------------------------------------------------------------------
__global__ __launch_bounds__(256) void transpose_cast(
    const float* __restrict__ W, ushort* __restrict__ Wt,
    int K, int Nn, int rowoff, int ldt) {
  __shared__ float tile[32][33];
  const int tx = threadIdx.x & 31, ty = threadIdx.x >> 5;  // ty: 0..7
  const int nb = blockIdx.x * 32, kb = blockIdx.y * 32;
#pragma unroll
  for (int s = 0; s < 4; ++s)
    tile[ty + 8 * s][tx] = W[(size_t)(kb + ty + 8 * s) * Nn + nb + tx];
  __syncthreads();
#pragma unroll
  for (int s = 0; s < 4; ++s)
    Wt[(size_t)(rowoff + nb + ty + 8 * s) * ldt + kb + tx] =
        f2bf(tile[tx][ty + 8 * s]);
}

// ---------------------------------------------------------------------------
// bf16 GEMM, C = A[M,K] @ Bt[N,K]^T
// 256x256 tile, BK=32, 8 waves (2 Mx4 N), per-wave out 128x64 (8x4 frags).
// Quad-buffered LDS; while computing tile t (buf t&3), stage tile t+3 into
// buf (t+3)&3 = (t-1)&3 whose readers (tile t-1) all passed this tile's
// barrier. One vmcnt + one barrier per K-tile; vmcnt(8) keeps 2 tiles of
// loads in flight across barriers (counted-vmcnt, T4).
// LDS granule swizzle: granule(row,s) = row*4 + ((s + (row>>1)) & 3)
// (involution-consistent: staging fetches source col s = ((g&3)-((g>>3)&3))&3,
//  reader adds ((lane>>4)+((lane>>1)&3))&3) -> 2-way banked ds_read_b128.
// EPI 0: +bias(select by n0), bf16 out   (QKV)
// EPI 1: relu(+bias), bf16 out           (FFN1)
// EPI 2: +bias +resid(bf16), fp32 out    (FFN2)
// ---------------------------------------------------------------------------
template <int EPI>
__global__ __launch_bounds__(512, 2) void gemm_bt(
    const ushort* __restrict__ A, const ushort* __restrict__ Bt,
    int N, int K, void* __restrict__ Cout,
    const float* __restrict__ bias0, const float* __restrict__ bias1,
    const float* __restrict__ bias2, const ushort* __restrict__ resid) {
  constexpr int BK = 32;
  // per buffer: A 8192 elems (256x32), B 8192 elems; 4 buffers = 128 KiB
  __shared__ __align__(16) ushort lds[4 * 16384];
  const int tid = threadIdx.x;
  const int wid = tid >> 6, lane = tid & 63;
  const int wm = wid >> 2, wn = wid & 3;
  const size_t m0 = (size_t)blockIdx.y * 256;
  const size_t n0 = (size_t)blockIdx.x * 256;
  const int NT = K / BK;

  // ---- staging: thread tid covers granule g = l*512 + tid of each 128-row
  // half (l=0,1). Linear LDS dest = base + tid*8 elems (wave-uniform + lane*16B).
  // Swizzled global source column slot: s = ((g&3) - ((g>>3)&3)) & 3.
  const int sgcol = (((tid & 3) - ((tid >> 3) & 3)) & 3) << 3;
  const ushort* a0 = A + (m0 + (tid >> 2)) * (size_t)K + sgcol;
  const ushort* b0 = Bt + (n0 + (tid >> 2)) * (size_t)K + sgcol;
  const size_t rowK = 128 * (size_t)K;
  ushort* ldst = &lds[tid * 8];

#define STAGE_T(t)                                                          \
  {                                                                         \
    ushort* d = ldst + ((t) & 3) * 16384;                                   \
    const ushort* ga = a0 + (size_t)(t) * BK;                               \
    const ushort* gb = b0 + (size_t)(t) * BK;                               \
    GLD16(ga, d);                                                           \
    GLD16(ga + rowK, d + 4096);                                             \
    GLD16(gb, d + 8192);                                                    \
    GLD16(gb + rowK, d + 12288);                                            \
  }

  // ---- reader: fragment (row = base + lane&15, k-slot s0 = lane>>4)
  // lives at granule row*4 + ((s0 + (row>>1)) & 3); base rows are
  // multiples of 16 so (row>>1)&3 == (lane>>1)&3.
  const int cswz = ((((lane >> 4) + ((lane >> 1) & 3)) & 3) << 3);
  const int arow = wm * 128 + (lane & 15);
  const int brow = wn * 64 + (lane & 15);

  f32x4 acc[8][4] = {};

  STAGE_T(0);
  STAGE_T(1);
  STAGE_T(2);

  for (int t = 0; t < NT; ++t) {
    // boundary: ensure tile t's 4 loads landed (leave tiles t+1,t+2 in flight)
    if (t < NT - 2) {
      asm volatile("s_waitcnt vmcnt(8)" ::: "memory");
    } else if (t == NT - 2) {
      asm volatile("s_waitcnt vmcnt(4)" ::: "memory");
    } else {
      asm volatile("s_waitcnt vmcnt(0)" ::: "memory");
    }
    __builtin_amdgcn_s_barrier();

    const ushort* lA = &lds[(t & 3) * 16384];
    const ushort* lB = lA + 8192;

    // stage tile t+3 into buf (t-1)&3 (its readers all passed this barrier)
    if (t + 3 < NT) STAGE_T(t + 3);

    bf16x8 af[8], bfr[4];
#pragma unroll
    for (int mi = 0; mi < 8; ++mi)
      af[mi] = *(const bf16x8*)&lA[(arow + mi * 16) * 32 + cswz];
#pragma unroll
    for (int ni = 0; ni < 4; ++ni)
      bfr[ni] = *(const bf16x8*)&lB[(brow + ni * 16) * 32 + cswz];

    __builtin_amdgcn_s_setprio(1);
#pragma unroll
    for (int mi = 0; mi < 8; ++mi)
#pragma unroll
      for (int ni = 0; ni < 4; ++ni)
        acc[mi][ni] = __builtin_amdgcn_mfma_f32_16x16x32_bf16(
            af[mi], bfr[ni], acc[mi][ni], 0, 0, 0);
    __builtin_amdgcn_s_setprio(0);
  }
#undef STAGE_T

  // epilogue: D col = lane&15, row = (lane>>4)*4 + j  (m89-verified)
  const int lm = lane & 15, lq = lane >> 4;
#pragma unroll
  for (int ni = 0; ni < 4; ++ni) {
    const size_t col = n0 + wn * 64 + ni * 16 + lm;
    float bv;
    if (EPI == 0) {
      const float* bp = (n0 < 512) ? bias0 : ((n0 < 1024) ? bias1 : bias2);
      bv = bp[col & 511];
    } else {
      bv = bias0[col];
    }
#pragma unroll
    for (int mi = 0; mi < 8; ++mi) {
#pragma unroll
      for (int j = 0; j < 4; ++j) {
        const size_t row = m0 + wm * 128 + mi * 16 + lq * 4 + j;
        float v = acc[mi][ni][j] + bv;
        if (EPI == 0) {
          ((ushort*)Cout)[row * N + col] = f2bf(v);
        } else if (EPI == 1) {
          ((ushort*)Cout)[row * N + col] = f2bf(fmaxf(v, 0.f));
        } else {
          v += bf2f(resid[row * N + col]);
          ((float*)Cout)[row * N + col] = v;
        }
      }
    }
  }
}

// ---------------------------------------------------------------------------
// Per-token attention (H=8, HD=64) + residual + LN1 -> y (bf16)
// One wave per token; lane = head-dim element d.
// Scores via 6-step transpose-reduce (63 shuffles); softmax in 8-lane groups;
// context via v_readlane broadcast.
// ---------------------------------------------------------------------------
__global__ __launch_bounds__(256) void attn_ln1(
    const ushort* __restrict__ qkv, const float* __restrict__ x,
    const float* __restrict__ g1, const float* __restrict__ b1,
    ushort* __restrict__ y) {
  const int lane = threadIdx.x & 63;
  const size_t t = (size_t)blockIdx.x * 4 + (threadIdx.x >> 6);
  const ushort* base = qkv + t * 1536;
  float qd[8], kd[8], vd[8];
#pragma unroll
  for (int h = 0; h < 8; ++h) {
    qd[h] = bf2f(base[h * 64 + lane]);
    kd[h] = bf2f(base[512 + h * 64 + lane]);
    vd[h] = bf2f(base[1024 + h * 64 + lane]);
  }

  const bool lb0 = lane & 1, lb1 = lane & 2, lb2 = lane & 4;
  const bool lb3 = lane & 8, lb4 = lane & 16, lb5 = lane & 32;

  float c1[32];
#pragma unroll
  for (int f = 0; f < 32; ++f) {
    const int i0 = 2 * f, i1 = 2 * f + 1;
    const float a0 = qd[i0 >> 3] * kd[i0 & 7];
    const float a1 = qd[i1 >> 3] * kd[i1 & 7];
    const float keep = lb0 ? a1 : a0;
    const float send = lb0 ? a0 : a1;
    c1[f] = keep + __shfl_xor(send, 1, 64);
  }
  float c2[16];
#pragma unroll
  for (int f = 0; f < 16; ++f) {
    const float keep = lb1 ? c1[2 * f + 1] : c1[2 * f];
    const float send = lb1 ? c1[2 * f] : c1[2 * f + 1];
    c2[f] = keep + __shfl_xor(send, 2, 64);
  }
  float c3[8];
#pragma unroll
  for (int f = 0; f < 8; ++f) {
    const float keep = lb2 ? c2[2 * f + 1] : c2[2 * f];
    const float send = lb2 ? c2[2 * f] : c2[2 * f + 1];
    c3[f] = keep + __shfl_xor(send, 4, 64);
  }
  float c4[4];
#pragma unroll
  for (int f = 0; f < 4; ++f) {
    const float keep = lb3 ? c3[2 * f + 1] : c3[2 * f];
    const float send = lb3 ? c3[2 * f] : c3[2 * f + 1];
    c4[f] = keep + __shfl_xor(send, 8, 64);
  }
  float c5[2];
#pragma unroll
  for (int f = 0; f < 2; ++f) {
    const float keep = lb4 ? c4[2 * f + 1] : c4[2 * f];
    const float send = lb4 ? c4[2 * f] : c4[2 * f + 1];
    c5[f] = keep + __shfl_xor(send, 16, 64);
  }
  const float keep = lb5 ? c5[1] : c5[0];
  const float send = lb5 ? c5[0] : c5[1];
  const float s = keep + __shfl_xor(send, 32, 64);  // raw score, i = lane

  float mx = s;
  mx = fmaxf(mx, __shfl_xor(mx, 1, 64));
  mx = fmaxf(mx, __shfl_xor(mx, 2, 64));
  mx = fmaxf(mx, __shfl_xor(mx, 4, 64));
  const float e = __expf((s - mx) * 0.125f);
  float sum = e;
  sum += __shfl_xor(sum, 1, 64);
  sum += __shfl_xor(sum, 2, 64);
  sum += __shfl_xor(sum, 4, 64);
  const float a = e * __builtin_amdgcn_rcpf(sum);

  const int ai = __float_as_int(a);
  float r[8];
#pragma unroll
  for (int h = 0; h < 8; ++h) {
    float c = 0.f;
#pragma unroll
    for (int g = 0; g < 8; ++g) {
      const float w = __int_as_float(__builtin_amdgcn_readlane(ai, h * 8 + g));
      c = fmaf(w, vd[g], c);
    }
    r[h] = x[t * 512 + h * 64 + lane] + c;
  }

  float sm = 0.f, sq = 0.f;
#pragma unroll
  for (int h = 0; h < 8; ++h) { sm += r[h]; sq += r[h] * r[h]; }
#pragma unroll
  for (int m = 1; m < 64; m <<= 1) {
    sm += __shfl_xor(sm, m, 64);
    sq += __shfl_xor(sq, m, 64);
  }
  const float mu = sm * (1.f / 512.f);
  const float var = sq * (1.f / 512.f) - mu * mu;
  const float rs = rsqrtf(var + 1e-5f);
#pragma unroll
  for (int h = 0; h < 8; ++h) {
    const int d = h * 64 + lane;
    y[t * 512 + d] = f2bf((r[h] - mu) * rs * g1[d] + b1[d]);
  }
}

// ---------------------------------------------------------------------------
// LN2(z) -> out fp32. One wave per token, float4-vectorized.
// ---------------------------------------------------------------------------
__global__ __launch_bounds__(256) void ln_out(
    const float* __restrict__ z, const float* __restrict__ g2,
    const float* __restrict__ b2, float* __restrict__ out) {
  const int lane = threadIdx.x & 63;
  const size_t t = (size_t)blockIdx.x * 4 + (threadIdx.x >> 6);
  const float4* zp = (const float4*)(z + t * 512);
  const float4 r0 = zp[lane], r1 = zp[lane + 64];
  float sm = r0.x + r0.y + r0.z + r0.w + r1.x + r1.y + r1.z + r1.w;
  float sq = r0.x * r0.x + r0.y * r0.y + r0.z * r0.z + r0.w * r0.w +
             r1.x * r1.x + r1.y * r1.y + r1.z * r1.z + r1.w * r1.w;
#pragma unroll
  for (int m = 1; m < 64; m <<= 1) {
    sm += __shfl_xor(sm, m, 64);
    sq += __shfl_xor(sq, m, 64);
  }
  const float mu = sm * (1.f / 512.f);
  const float rs = rsqrtf(sq * (1.f / 512.f) - mu * mu + 1e-5f);
  const float4* g4 = (const float4*)g2;
  const float4* b4 = (const float4*)b2;
  float4* o4 = (float4*)(out + t * 512);
  const float4 ga = g4[lane], gb = g4[lane + 64];
  const float4 ba = b4[lane], bb = b4[lane + 64];
  float4 oa, ob;
  oa.x = (r0.x - mu) * rs * ga.x + ba.x;
  oa.y = (r0.y - mu) * rs * ga.y + ba.y;
  oa.z = (r0.z - mu) * rs * ga.z + ba.z;
  oa.w = (r0.w - mu) * rs * ga.w + ba.w;
  ob.x = (r1.x - mu) * rs * gb.x + bb.x;
  ob.y = (r1.y - mu) * rs * gb.y + bb.y;
  ob.z = (r1.z - mu) * rs * gb.z + bb.z;
  ob.w = (r1.w - mu) * rs * gb.w + bb.w;
  o4[lane] = oa;
  o4[lane + 64] = ob;
}

// ---------------------------------------------------------------------------
extern "C" void kernel_launch(void* const* d_in, const int* in_sizes, int n_in,
                              void* d_out, int out_size, void* d_ws,
                              size_t ws_size, hipStream_t stream) {
  const float* x    = (const float*)d_in[0];
  const float* Wq   = (const float*)d_in[1];
  const float* bq   = (const float*)d_in[2];
  const float* Wk   = (const float*)d_in[3];
  const float* bk   = (const float*)d_in[4];
  const float* Wv   = (const float*)d_in[5];
  const float* bv   = (const float*)d_in[6];
  const float* ln1g = (const float*)d_in[7];
  const float* ln1b = (const float*)d_in[8];
  const float* W1   = (const float*)d_in[9];
  const float* b1   = (const float*)d_in[10];
  const float* W2   = (const float*)d_in[11];
  const float* b2   = (const float*)d_in[12];
  const float* ln2g = (const float*)d_in[13];
  const float* ln2b = (const float*)d_in[14];
  float* out = (float*)d_out;

  const int Ntok = in_sizes[0] / 512;  // 65536

  // ---- workspace layout: weights once, then chunk buffers (9 KiB/token)
  char* ws = (char*)d_ws;
  ushort* Wqkvt = (ushort*)ws;                       // [1536][512]
  ushort* W1t   = Wqkvt + (size_t)1536 * 512;        // [2048][512]
  ushort* W2t   = W1t + (size_t)2048 * 512;          // [512][2048]
  const size_t woff = ((size_t)1536 * 512 + (size_t)2048 * 512 +
                       (size_t)512 * 2048) * 2;      // 5.5 MiB

  size_t avail = (ws_size > woff) ? (ws_size - woff) : 0;
  long long Cll = (long long)(avail / 9216);
  Cll = (Cll / 256) * 256;
  if (Cll > 32768) Cll = 32768;
  if (Cll > Ntok) Cll = Ntok;
  if (Cll < 256) Cll = 256;
  const int C = (int)Cll;

  char* cb = ws + woff;
  ushort* xb  = (ushort*)cb;                          // [C][512] bf16
  ushort* y   = xb + (size_t)C * 512;                 // [C][512] bf16
  ushort* qkv = y + (size_t)C * 512;                  // [C][1536] bf16
  ushort* hb  = qkv + (size_t)C * 1536;               // [C][2048] bf16
  float*  z   = (float*)qkv;                          // [C][512] f32 (aliases qkv)

  // ---- weight transposes (once)
  transpose_cast<<<dim3(16, 16), dim3(256), 0, stream>>>(Wq, Wqkvt, 512, 512, 0, 512);
  transpose_cast<<<dim3(16, 16), dim3(256), 0, stream>>>(Wk, Wqkvt, 512, 512, 512, 512);
  transpose_cast<<<dim3(16, 16), dim3(256), 0, stream>>>(Wv, Wqkvt, 512, 512, 1024, 512);
  transpose_cast<<<dim3(64, 16), dim3(256), 0, stream>>>(W1, W1t, 512, 2048, 0, 512);
  transpose_cast<<<dim3(16, 64), dim3(256), 0, stream>>>(W2, W2t, 2048, 512, 0, 2048);

  // ---- chunked pipeline
  for (int t0 = 0; t0 < Ntok; t0 += C) {
    const int Cc = (Ntok - t0 < C) ? (Ntok - t0) : C;   // multiple of 256
    const float* xc = x + (size_t)t0 * 512;

    cast_f32_bf16<<<dim3((Cc * 512) / 2048), dim3(256), 0, stream>>>(xc, xb);

    gemm_bt<0><<<dim3(1536 / 256, Cc / 256), dim3(512), 0, stream>>>(
        xb, Wqkvt, 1536, 512, qkv, bq, bk, bv, nullptr);

    attn_ln1<<<dim3(Cc / 4), dim3(256), 0, stream>>>(qkv, xc, ln1g, ln1b, y);

    gemm_bt<1><<<dim3(2048 / 256, Cc / 256), dim3(512), 0, stream>>>(
        y, W1t, 2048, 512, hb, b1, nullptr, nullptr, nullptr);

    gemm_bt<2><<<dim3(512 / 256, Cc / 256), dim3(512), 0, stream>>>(
        hb, W2t, 512, 2048, z, b2, nullptr, nullptr, y);

    ln_out<<<dim3(Cc / 4), dim3(256), 0, stream>>>(
        z, ln2g, ln2b, out + (size_t)t0 * 512);
  }
}

// Round 5
// 666.841 us; speedup vs baseline: 1.5149x; 1.1711x over previous
//
#include <hip/hip_runtime.h>
#include <cstdint>

// ---------------------------------------------------------------------------
// TransformerLayer on MI355X (gfx950)
// Chunked pipeline (chunk C tokens, per-token ws = 9 KiB):
//   once: transpose-cast weights -> bf16 [N][K]
//   per chunk:
//     1. cast x -> bf16 (xb)
//     2. GEMM qkv = xb @ [Wq|Wk|Wv] + bias          (bf16 out, EPI=0)
//     3. attn (per-token 8x8) + residual + LN1 -> y (bf16)
//     4. GEMM h = relu(y @ W1 + b1)                 (bf16 out, EPI=1)
//     5. GEMM z = h @ W2 + b2 + y                   (fp32 out, EPI=2, z aliases qkv)
//     6. LN2(z) -> out (fp32)
// GEMM: 256x256 tile, BK=32, quad-buffered LDS (128 KiB), counted vmcnt(8),
// 2-phase K-tile (16 MFMA per barrier), granule-swizzled LDS (T2, 0 bank
// conflicts measured), XCD-bijective block swizzle (T1), setprio (T5).
// ---------------------------------------------------------------------------

typedef __attribute__((ext_vector_type(8))) short bf16x8;
typedef __attribute__((ext_vector_type(4))) float f32x4;
typedef __attribute__((ext_vector_type(8))) unsigned short u16x8;

__device__ __forceinline__ float bf2f(unsigned short u) {
  union { unsigned int i; float f; } v; v.i = ((unsigned int)u) << 16; return v.f;
}
__device__ __forceinline__ unsigned short f2bf(float f) {
  union { float f; unsigned int i; } v; v.f = f;
  unsigned int r = v.i + 0x7FFFu + ((v.i >> 16) & 1u);   // round-nearest-even
  return (unsigned short)(r >> 16);
}

#define GLD16(g, l)                                                         \
  __builtin_amdgcn_global_load_lds(                                         \
      (const __attribute__((address_space(1))) void*)(g),                   \
      (__attribute__((address_space(3))) void*)(l), 16, 0, 0)

// ---------------------------------------------------------------------------
// fp32 -> bf16 cast, 8 elements/thread, vectorized
// ---------------------------------------------------------------------------
__global__ __launch_bounds__(256) void cast_f32_bf16(
    const float* __restrict__ in, ushort* __restrict__ out) {
  const size_t i = (size_t)blockIdx.x * 256 + threadIdx.x;
  const float4* p = (const float4*)in + i * 2;
  float4 a = p[0], b = p[1];
  u16x8 r;
  r[0] = f2bf(a.x); r[1] = f2bf(a.y); r[2] = f2bf(a.z); r[3] = f2bf(a.w);
  r[4] = f2bf(b.x); r[5] = f2bf(b.y); r[6] = f2bf(b.z); r[7] = f2bf(b.w);
  ((u16x8*)out)[i] = r;
}

// ---------------------------------------------------------------------------
// Transpose-cast: W fp32 [K][Nn] row-major -> Wt bf16 [rowoff+Nn][ldt=K]
// ---------------------------------------------------------------------------
__global__ __launch_bounds__(256) void transpose_cast(
    const float* __restrict__ W, ushort* __restrict__ Wt,
    int K, int Nn, int rowoff, int ldt) {
  __shared__ float tile[32][33];
  const int tx = threadIdx.x & 31, ty = threadIdx.x >> 5;  // ty: 0..7
  const int nb = blockIdx.x * 32, kb = blockIdx.y * 32;
#pragma unroll
  for (int s = 0; s < 4; ++s)
    tile[ty + 8 * s][tx] = W[(size_t)(kb + ty + 8 * s) * Nn + nb + tx];
  __syncthreads();
#pragma unroll
  for (int s = 0; s < 4; ++s)
    Wt[(size_t)(rowoff + nb + ty + 8 * s) * ldt + kb + tx] =
        f2bf(tile[tx][ty + 8 * s]);
}

// ---------------------------------------------------------------------------
// bf16 GEMM, C = A[M,K] @ Bt[N,K]^T
// 256x256 tile, BK=32, 8 waves (2M x 4N), per-wave out 128x64 (8x4 frags).
// Quad-buffered LDS; stage tile t+3 into buf (t-1)&3 (readers passed >=1
// barrier + memory-latency margin ago). vmcnt(8) keeps 2 tiles in flight.
// K-tile split into 2 phases of 16 MFMA each, barrier after each phase.
// XCD-bijective swizzle: each XCD owns a contiguous row-band (A fetched
// once per band; B panel L2-resident per XCD).
// ---------------------------------------------------------------------------
template <int EPI>
__global__ __launch_bounds__(512, 2) void gemm_bt(
    const ushort* __restrict__ A, const ushort* __restrict__ Bt,
    int N, int K, void* __restrict__ Cout,
    const float* __restrict__ bias0, const float* __restrict__ bias1,
    const float* __restrict__ bias2, const ushort* __restrict__ resid) {
  constexpr int BK = 32;
  __shared__ __align__(16) ushort lds[4 * 16384];
  const int tid = threadIdx.x;
  const int wid = tid >> 6, lane = tid & 63;
  const int wm = wid >> 2, wn = wid & 3;

  // ---- XCD-aware bijective block swizzle (m204)
  const int gx = gridDim.x;
  const int nwg = gx * gridDim.y;
  const int orig = blockIdx.y * gx + blockIdx.x;
  const int q = nwg >> 3, r = nwg & 7;
  const int xcd = orig & 7, loc = orig >> 3;
  const int swz = (xcd < r) ? (xcd * (q + 1) + loc)
                            : (r * (q + 1) + (xcd - r) * q + loc);
  const size_t m0 = (size_t)(swz / gx) * 256;
  const size_t n0 = (size_t)(swz % gx) * 256;
  const int NT = K / BK;

  // staging (byte-identical math to the verified r4 kernel):
  // thread tid covers granule tid of each 128-row half; linear LDS dest
  // = base + tid*16B; swizzled global source slot s = ((g&3)-((g>>3)&3))&3.
  const int sgcol = (((tid & 3) - ((tid >> 3) & 3)) & 3) << 3;
  const ushort* a0 = A + (m0 + (tid >> 2)) * (size_t)K + sgcol;
  const ushort* b0 = Bt + (n0 + (tid >> 2)) * (size_t)K + sgcol;
  const size_t rowK = 128 * (size_t)K;
  ushort* ldst = &lds[tid * 8];

#define STAGE_A(t)                                                          \
  {                                                                         \
    ushort* d = ldst + ((t) & 3) * 16384;                                   \
    const ushort* g = a0 + (size_t)(t) * BK;                                \
    GLD16(g, d);                                                            \
    GLD16(g + rowK, d + 4096);                                              \
  }
#define STAGE_B(t)                                                          \
  {                                                                         \
    ushort* d = ldst + ((t) & 3) * 16384 + 8192;                            \
    const ushort* g = b0 + (size_t)(t) * BK;                                \
    GLD16(g, d);                                                            \
    GLD16(g + rowK, d + 4096);                                              \
  }

  // reader: fragment (row, k-slot lane>>4) at granule row*4 + ((s0+(row>>1))&3)
  const int cswz = ((((lane >> 4) + ((lane >> 1) & 3)) & 3) << 3);
  const int arow = wm * 128 + (lane & 15);
  const int brow = wn * 64 + (lane & 15);

  f32x4 acc[8][4] = {};

  STAGE_A(0); STAGE_B(0);
  STAGE_A(1); STAGE_B(1);
  STAGE_A(2); STAGE_B(2);

  for (int t = 0; t < NT; ++t) {
    // tile t's 4 loads landed; keep tiles t+1,t+2 (8 loads) in flight
    if (t < NT - 2) {
      asm volatile("s_waitcnt vmcnt(8)" ::: "memory");
    } else if (t == NT - 2) {
      asm volatile("s_waitcnt vmcnt(4)" ::: "memory");
    } else {
      asm volatile("s_waitcnt vmcnt(0)" ::: "memory");
    }
    __builtin_amdgcn_s_barrier();

    const ushort* lA = &lds[(t & 3) * 16384];
    const ushort* lB = lA + 8192;

    // ---- phase 1: frags mi 0-3 + all B; stage A-part of t+3
    bf16x8 af[4], bfr[4];
#pragma unroll
    for (int mi = 0; mi < 4; ++mi)
      af[mi] = *(const bf16x8*)&lA[(arow + mi * 16) * 32 + cswz];
#pragma unroll
    for (int ni = 0; ni < 4; ++ni)
      bfr[ni] = *(const bf16x8*)&lB[(brow + ni * 16) * 32 + cswz];
    if (t + 3 < NT) STAGE_A(t + 3);
    __builtin_amdgcn_s_setprio(1);
#pragma unroll
    for (int mi = 0; mi < 4; ++mi)
#pragma unroll
      for (int ni = 0; ni < 4; ++ni)
        acc[mi][ni] = __builtin_amdgcn_mfma_f32_16x16x32_bf16(
            af[mi], bfr[ni], acc[mi][ni], 0, 0, 0);
    __builtin_amdgcn_s_setprio(0);
    __builtin_amdgcn_s_barrier();

    // ---- phase 2: frags mi 4-7; stage B-part of t+3
    bf16x8 ag[4];
#pragma unroll
    for (int mi = 0; mi < 4; ++mi)
      ag[mi] = *(const bf16x8*)&lA[(arow + (mi + 4) * 16) * 32 + cswz];
    if (t + 3 < NT) STAGE_B(t + 3);
    __builtin_amdgcn_s_setprio(1);
#pragma unroll
    for (int mi = 0; mi < 4; ++mi)
#pragma unroll
      for (int ni = 0; ni < 4; ++ni)
        acc[mi + 4][ni] = __builtin_amdgcn_mfma_f32_16x16x32_bf16(
            ag[mi], bfr[ni], acc[mi + 4][ni], 0, 0, 0);
    __builtin_amdgcn_s_setprio(0);
  }
#undef STAGE_A
#undef STAGE_B

  // epilogue: D col = lane&15, row = (lane>>4)*4 + j (m89-verified).
  // mi/j outer, ni inner: the four 32-B segments of a row's 128-B line
  // are issued back-to-back (write-coalescing friendly).
  const int lm = lane & 15, lq = lane >> 4;
  size_t col[4];
  float bv[4];
#pragma unroll
  for (int ni = 0; ni < 4; ++ni) {
    col[ni] = n0 + wn * 64 + ni * 16 + lm;
    if (EPI == 0) {
      const float* bp = (n0 < 512) ? bias0 : ((n0 < 1024) ? bias1 : bias2);
      bv[ni] = bp[col[ni] & 511];
    } else {
      bv[ni] = bias0[col[ni]];
    }
  }
#pragma unroll
  for (int mi = 0; mi < 8; ++mi) {
#pragma unroll
    for (int j = 0; j < 4; ++j) {
      const size_t row = m0 + wm * 128 + mi * 16 + lq * 4 + j;
#pragma unroll
      for (int ni = 0; ni < 4; ++ni) {
        float v = acc[mi][ni][j] + bv[ni];
        if (EPI == 0) {
          ((ushort*)Cout)[row * N + col[ni]] = f2bf(v);
        } else if (EPI == 1) {
          ((ushort*)Cout)[row * N + col[ni]] = f2bf(fmaxf(v, 0.f));
        } else {
          v += bf2f(resid[row * N + col[ni]]);
          ((float*)Cout)[row * N + col[ni]] = v;
        }
      }
    }
  }
}

// ---------------------------------------------------------------------------
// Per-token attention (H=8, HD=64) + residual + LN1 -> y (bf16)
// One wave per token; lane = head-dim element d.
// Scores via 6-step transpose-reduce (63 shuffles); softmax in 8-lane groups;
// context via v_readlane broadcast.
// ---------------------------------------------------------------------------
__global__ __launch_bounds__(256) void attn_ln1(
    const ushort* __restrict__ qkv, const float* __restrict__ x,
    const float* __restrict__ g1, const float* __restrict__ b1,
    ushort* __restrict__ y) {
  const int lane = threadIdx.x & 63;
  const size_t t = (size_t)blockIdx.x * 4 + (threadIdx.x >> 6);
  const ushort* base = qkv + t * 1536;
  float qd[8], kd[8], vd[8];
#pragma unroll
  for (int h = 0; h < 8; ++h) {
    qd[h] = bf2f(base[h * 64 + lane]);
    kd[h] = bf2f(base[512 + h * 64 + lane]);
    vd[h] = bf2f(base[1024 + h * 64 + lane]);
  }

  const bool lb0 = lane & 1, lb1 = lane & 2, lb2 = lane & 4;
  const bool lb3 = lane & 8, lb4 = lane & 16, lb5 = lane & 32;

  float c1[32];
#pragma unroll
  for (int f = 0; f < 32; ++f) {
    const int i0 = 2 * f, i1 = 2 * f + 1;
    const float a0 = qd[i0 >> 3] * kd[i0 & 7];
    const float a1 = qd[i1 >> 3] * kd[i1 & 7];
    const float keep = lb0 ? a1 : a0;
    const float send = lb0 ? a0 : a1;
    c1[f] = keep + __shfl_xor(send, 1, 64);
  }
  float c2[16];
#pragma unroll
  for (int f = 0; f < 16; ++f) {
    const float keep = lb1 ? c1[2 * f + 1] : c1[2 * f];
    const float send = lb1 ? c1[2 * f] : c1[2 * f + 1];
    c2[f] = keep + __shfl_xor(send, 2, 64);
  }
  float c3[8];
#pragma unroll
  for (int f = 0; f < 8; ++f) {
    const float keep = lb2 ? c2[2 * f + 1] : c2[2 * f];
    const float send = lb2 ? c2[2 * f] : c2[2 * f + 1];
    c3[f] = keep + __shfl_xor(send, 4, 64);
  }
  float c4[4];
#pragma unroll
  for (int f = 0; f < 4; ++f) {
    const float keep = lb3 ? c3[2 * f + 1] : c3[2 * f];
    const float send = lb3 ? c3[2 * f] : c3[2 * f + 1];
    c4[f] = keep + __shfl_xor(send, 8, 64);
  }
  float c5[2];
#pragma unroll
  for (int f = 0; f < 2; ++f) {
    const float keep = lb4 ? c4[2 * f + 1] : c4[2 * f];
    const float send = lb4 ? c4[2 * f] : c4[2 * f + 1];
    c5[f] = keep + __shfl_xor(send, 16, 64);
  }
  const float keep = lb5 ? c5[1] : c5[0];
  const float send = lb5 ? c5[0] : c5[1];
  const float s = keep + __shfl_xor(send, 32, 64);  // raw score, i = lane

  float mx = s;
  mx = fmaxf(mx, __shfl_xor(mx, 1, 64));
  mx = fmaxf(mx, __shfl_xor(mx, 2, 64));
  mx = fmaxf(mx, __shfl_xor(mx, 4, 64));
  const float e = __expf((s - mx) * 0.125f);
  float sum = e;
  sum += __shfl_xor(sum, 1, 64);
  sum += __shfl_xor(sum, 2, 64);
  sum += __shfl_xor(sum, 4, 64);
  const float a = e * __builtin_amdgcn_rcpf(sum);

  const int ai = __float_as_int(a);
  float r[8];
#pragma unroll
  for (int h = 0; h < 8; ++h) {
    float c = 0.f;
#pragma unroll
    for (int g = 0; g < 8; ++g) {
      const float w = __int_as_float(__builtin_amdgcn_readlane(ai, h * 8 + g));
      c = fmaf(w, vd[g], c);
    }
    r[h] = x[t * 512 + h * 64 + lane] + c;
  }

  float sm = 0.f, sq = 0.f;
#pragma unroll
  for (int h = 0; h < 8; ++h) { sm += r[h]; sq += r[h] * r[h]; }
#pragma unroll
  for (int m = 1; m < 64; m <<= 1) {
    sm += __shfl_xor(sm, m, 64);
    sq += __shfl_xor(sq, m, 64);
  }
  const float mu = sm * (1.f / 512.f);
  const float var = sq * (1.f / 512.f) - mu * mu;
  const float rs = rsqrtf(var + 1e-5f);
#pragma unroll
  for (int h = 0; h < 8; ++h) {
    const int d = h * 64 + lane;
    y[t * 512 + d] = f2bf((r[h] - mu) * rs * g1[d] + b1[d]);
  }
}

// ---------------------------------------------------------------------------
// LN2(z) -> out fp32. One wave per token, float4-vectorized.
// ---------------------------------------------------------------------------
__global__ __launch_bounds__(256) void ln_out(
    const float* __restrict__ z, const float* __restrict__ g2,
    const float* __restrict__ b2, float* __restrict__ out) {
  const int lane = threadIdx.x & 63;
  const size_t t = (size_t)blockIdx.x * 4 + (threadIdx.x >> 6);
  const float4* zp = (const float4*)(z + t * 512);
  const float4 r0 = zp[lane], r1 = zp[lane + 64];
  float sm = r0.x + r0.y + r0.z + r0.w + r1.x + r1.y + r1.z + r1.w;
  float sq = r0.x * r0.x + r0.y * r0.y + r0.z * r0.z + r0.w * r0.w +
             r1.x * r1.x + r1.y * r1.y + r1.z * r1.z + r1.w * r1.w;
#pragma unroll
  for (int m = 1; m < 64; m <<= 1) {
    sm += __shfl_xor(sm, m, 64);
    sq += __shfl_xor(sq, m, 64);
  }
  const float mu = sm * (1.f / 512.f);
  const float rs = rsqrtf(sq * (1.f / 512.f) - mu * mu + 1e-5f);
  const float4* g4 = (const float4*)g2;
  const float4* b4 = (const float4*)b2;
  float4* o4 = (float4*)(out + t * 512);
  const float4 ga = g4[lane], gb = g4[lane + 64];
  const float4 ba = b4[lane], bb = b4[lane + 64];
  float4 oa, ob;
  oa.x = (r0.x - mu) * rs * ga.x + ba.x;
  oa.y = (r0.y - mu) * rs * ga.y + ba.y;
  oa.z = (r0.z - mu) * rs * ga.z + ba.z;
  oa.w = (r0.w - mu) * rs * ga.w + ba.w;
  ob.x = (r1.x - mu) * rs * gb.x + bb.x;
  ob.y = (r1.y - mu) * rs * gb.y + bb.y;
  ob.z = (r1.z - mu) * rs * gb.z + bb.z;
  ob.w = (r1.w - mu) * rs * gb.w + bb.w;
  o4[lane] = oa;
  o4[lane + 64] = ob;
}

// ---------------------------------------------------------------------------
extern "C" void kernel_launch(void* const* d_in, const int* in_sizes, int n_in,
                              void* d_out, int out_size, void* d_ws,
                              size_t ws_size, hipStream_t stream) {
  const float* x    = (const float*)d_in[0];
  const float* Wq   = (const float*)d_in[1];
  const float* bq   = (const float*)d_in[2];
  const float* Wk   = (const float*)d_in[3];
  const float* bk   = (const float*)d_in[4];
  const float* Wv   = (const float*)d_in[5];
  const float* bv   = (const float*)d_in[6];
  const float* ln1g = (const float*)d_in[7];
  const float* ln1b = (const float*)d_in[8];
  const float* W1   = (const float*)d_in[9];
  const float* b1   = (const float*)d_in[10];
  const float* W2   = (const float*)d_in[11];
  const float* b2   = (const float*)d_in[12];
  const float* ln2g = (const float*)d_in[13];
  const float* ln2b = (const float*)d_in[14];
  float* out = (float*)d_out;

  const int Ntok = in_sizes[0] / 512;  // 65536

  // ---- workspace layout: weights once, then chunk buffers (9 KiB/token)
  char* ws = (char*)d_ws;
  ushort* Wqkvt = (ushort*)ws;                       // [1536][512]
  ushort* W1t   = Wqkvt + (size_t)1536 * 512;        // [2048][512]
  ushort* W2t   = W1t + (size_t)2048 * 512;          // [512][2048]
  const size_t woff = ((size_t)1536 * 512 + (size_t)2048 * 512 +
                       (size_t)512 * 2048) * 2;      // 5.5 MiB

  size_t avail = (ws_size > woff) ? (ws_size - woff) : 0;
  long long Cll = (long long)(avail / 9216);
  Cll = (Cll / 256) * 256;
  if (Cll > 32768) Cll = 32768;
  if (Cll > Ntok) Cll = Ntok;
  if (Cll < 256) Cll = 256;
  const int C = (int)Cll;

  char* cb = ws + woff;
  ushort* xb  = (ushort*)cb;                          // [C][512] bf16
  ushort* y   = xb + (size_t)C * 512;                 // [C][512] bf16
  ushort* qkv = y + (size_t)C * 512;                  // [C][1536] bf16
  ushort* hb  = qkv + (size_t)C * 1536;               // [C][2048] bf16
  float*  z   = (float*)qkv;                          // [C][512] f32 (aliases qkv)

  // ---- weight transposes (once)
  transpose_cast<<<dim3(16, 16), dim3(256), 0, stream>>>(Wq, Wqkvt, 512, 512, 0, 512);
  transpose_cast<<<dim3(16, 16), dim3(256), 0, stream>>>(Wk, Wqkvt, 512, 512, 512, 512);
  transpose_cast<<<dim3(16, 16), dim3(256), 0, stream>>>(Wv, Wqkvt, 512, 512, 1024, 512);
  transpose_cast<<<dim3(64, 16), dim3(256), 0, stream>>>(W1, W1t, 512, 2048, 0, 512);
  transpose_cast<<<dim3(16, 64), dim3(256), 0, stream>>>(W2, W2t, 2048, 512, 0, 2048);

  // ---- chunked pipeline
  for (int t0 = 0; t0 < Ntok; t0 += C) {
    const int Cc = (Ntok - t0 < C) ? (Ntok - t0) : C;   // multiple of 256
    const float* xc = x + (size_t)t0 * 512;

    cast_f32_bf16<<<dim3((Cc * 512) / 2048), dim3(256), 0, stream>>>(xc, xb);

    gemm_bt<0><<<dim3(1536 / 256, Cc / 256), dim3(512), 0, stream>>>(
        xb, Wqkvt, 1536, 512, qkv, bq, bk, bv, nullptr);

    attn_ln1<<<dim3(Cc / 4), dim3(256), 0, stream>>>(qkv, xc, ln1g, ln1b, y);

    gemm_bt<1><<<dim3(2048 / 256, Cc / 256), dim3(512), 0, stream>>>(
        y, W1t, 2048, 512, hb, b1, nullptr, nullptr, nullptr);

    gemm_bt<2><<<dim3(512 / 256, Cc / 256), dim3(512), 0, stream>>>(
        hb, W2t, 512, 2048, z, b2, nullptr, nullptr, y);

    ln_out<<<dim3(Cc / 4), dim3(256), 0, stream>>>(
        z, ln2g, ln2b, out + (size_t)t0 * 512);
  }
}